// Round 2
// baseline (4698.510 us; speedup 1.0000x reference)
//
#include <hip/hip_runtime.h>
#include <hip/hip_bf16.h>

#define EMB   1024
#define HID   1024
#define NBATCH 64
#define SEQ   128
#define NGATE 4096   // 4*HID
#define NBLK  256    // recurrence grid

typedef __attribute__((ext_vector_type(8))) short bf16x8;
typedef __attribute__((ext_vector_type(4))) float f32x4;

__device__ __forceinline__ unsigned short f2bf(float f) {
    unsigned int u = __float_as_uint(f);
    unsigned int r = (u + 0x7FFFu + ((u >> 16) & 1u)) >> 16;
    return (unsigned short)r;
}

__device__ __forceinline__ bf16x8 pack8(float4 a, float4 b) {
    bf16x8 r;
    r[0] = (short)f2bf(a.x); r[1] = (short)f2bf(a.y);
    r[2] = (short)f2bf(a.z); r[3] = (short)f2bf(a.w);
    r[4] = (short)f2bf(b.x); r[5] = (short)f2bf(b.y);
    r[6] = (short)f2bf(b.z); r[7] = (short)f2bf(b.w);
    return r;
}

__device__ __forceinline__ float sigmoidf_(float x) { return 1.0f / (1.0f + __expf(-x)); }
__device__ __forceinline__ float tanhf_(float x)    { return 1.0f - 2.0f / (1.0f + __expf(2.0f * x)); }

// ---- hand-rolled grid barrier (no cooperative launch needed) -----------
// Safe because all NBLK blocks are guaranteed co-resident by capacity:
// 256 blocks, ~4KB LDS, ~200 VGPR -> >= 2 blocks/CU capacity on 256 CUs.
__device__ __forceinline__ void gbar(unsigned* cnt, unsigned* gen) {
    __syncthreads();
    if (threadIdx.x == 0) {
        __threadfence();   // release: my h-writes visible before arrival
        unsigned g = __hip_atomic_load(gen, __ATOMIC_RELAXED, __HIP_MEMORY_SCOPE_AGENT);
        unsigned a = atomicAdd(cnt, 1u);
        if (a == NBLK - 1u) {
            __hip_atomic_store(cnt, 0u, __ATOMIC_RELAXED, __HIP_MEMORY_SCOPE_AGENT);
            __hip_atomic_store(gen, g + 1u, __ATOMIC_RELEASE, __HIP_MEMORY_SCOPE_AGENT);
        } else {
            long spins = 0;
            while (__hip_atomic_load(gen, __ATOMIC_RELAXED, __HIP_MEMORY_SCOPE_AGENT) == g &&
                   spins < 1000000L) {
                __builtin_amdgcn_s_sleep(8);
                ++spins;
            }
        }
        __threadfence();   // acquire: invalidate L1 before reading others' h
    }
    __syncthreads();
}

// ---- prep kernels ------------------------------------------------------

// X[t*64+b][k] = bf16(emb[inputs[b][t]][k]);  grid 8192, block 256
__global__ void gather_x(const float* __restrict__ emb, const int* __restrict__ inp,
                         unsigned short* __restrict__ xbf) {
    int m = blockIdx.x;          // m = t*64 + b
    int t = m >> 6, b = m & 63;
    int tok = inp[b * SEQ + t];
    float4 v = ((const float4*)(emb + (long)tok * EMB))[threadIdx.x];
    ushort4 o;
    o.x = f2bf(v.x); o.y = f2bf(v.y); o.z = f2bf(v.z); o.w = f2bf(v.w);
    ((ushort4*)(xbf + (long)m * EMB))[threadIdx.x] = o;
}

// W_ih -> bf16; grid 4096, block 256
__global__ void conv_w(const float* __restrict__ w, unsigned short* __restrict__ wbf) {
    long i = (long)blockIdx.x * 1024 + (long)threadIdx.x * 4;
    float4 v = *(const float4*)(w + i);
    ushort4 o;
    o.x = f2bf(v.x); o.y = f2bf(v.y); o.z = f2bf(v.z); o.w = f2bf(v.w);
    *(ushort4*)(wbf + i) = o;
}

// bsum = b_ih + b_hh; grid 16, block 256
__global__ void bsum_k(const float* __restrict__ bi, const float* __restrict__ bh,
                       float* __restrict__ bs) {
    int i = blockIdx.x * 256 + threadIdx.x;
    bs[i] = bi[i] + bh[i];
}

// ---- input GEMM: XW[t][n][b] = sum_k X[t*64+b][k]*W_ih[n][k] + bsum[n] ----
__global__ __launch_bounds__(256) void gemm_xw(const unsigned short* __restrict__ A,
                                               const unsigned short* __restrict__ Bw,
                                               const float* __restrict__ bsum,
                                               float* __restrict__ XW) {
    __shared__ unsigned short As[128][40];
    __shared__ unsigned short Bs[128][40];
    int bx = blockIdx.x;             // N tile (0..31)
    int by = blockIdx.y;             // M tile (0..63)
    int tid = threadIdx.x;
    int w = tid >> 6, l = tid & 63;
    int wm = w >> 1, wn = w & 1;
    int lr = l & 15, lk = l >> 4;

    f32x4 acc[4][4];
#pragma unroll
    for (int ni = 0; ni < 4; ++ni) {
        float bsv = bsum[bx * 128 + wn * 64 + ni * 16 + lr];
#pragma unroll
        for (int mi = 0; mi < 4; ++mi) {
            acc[mi][ni][0] = bsv; acc[mi][ni][1] = bsv;
            acc[mi][ni][2] = bsv; acc[mi][ni][3] = bsv;
        }
    }

    int sr = tid >> 1;
    int sc = (tid & 1) * 16;
    const unsigned short* ga = A  + (long)(by * 128 + sr) * 1024 + sc;
    const unsigned short* gb = Bw + (long)(bx * 128 + sr) * 1024 + sc;

    for (int kt = 0; kt < 32; ++kt) {
        uint4 va0 = *(const uint4*)(ga);
        uint4 va1 = *(const uint4*)(ga + 8);
        uint4 vb0 = *(const uint4*)(gb);
        uint4 vb1 = *(const uint4*)(gb + 8);
        *(uint4*)&As[sr][sc]     = va0;
        *(uint4*)&As[sr][sc + 8] = va1;
        *(uint4*)&Bs[sr][sc]     = vb0;
        *(uint4*)&Bs[sr][sc + 8] = vb1;
        __syncthreads();

        bf16x8 af[4], bfr[4];
#pragma unroll
        for (int mi = 0; mi < 4; ++mi)
            af[mi] = *(const bf16x8*)&As[wm * 64 + mi * 16 + lr][lk * 8];
#pragma unroll
        for (int ni = 0; ni < 4; ++ni)
            bfr[ni] = *(const bf16x8*)&Bs[wn * 64 + ni * 16 + lr][lk * 8];
#pragma unroll
        for (int mi = 0; mi < 4; ++mi)
#pragma unroll
            for (int ni = 0; ni < 4; ++ni)
                acc[mi][ni] = __builtin_amdgcn_mfma_f32_16x16x32_bf16(af[mi], bfr[ni], acc[mi][ni], 0, 0, 0);
        __syncthreads();
        ga += 32; gb += 32;
    }

#pragma unroll
    for (int mi = 0; mi < 4; ++mi) {
        int mg = by * 128 + wm * 64 + mi * 16 + lk * 4;
        int tt = mg >> 6;
        int bb = mg & 63;
#pragma unroll
        for (int ni = 0; ni < 4; ++ni) {
            int nn = bx * 128 + wn * 64 + ni * 16 + lr;
            *(f32x4*)(XW + (long)tt * (NGATE * 64) + (long)nn * 64 + bb) = acc[mi][ni];
        }
    }
}

// ---- recurrence (normal launch + own grid barrier) ---------------------
// 256 WGs x 256 thr. WG g owns hidden units g*4..g*4+3 (16 gate rows).
// W_hh frags live in registers (32 x bf16x8). h ping-pongs via bf16 global buf.
__global__ __launch_bounds__(256) void lstm_rec(const float* __restrict__ Whh,
                                                const float* __restrict__ XW,
                                                unsigned short* __restrict__ hbuf,
                                                unsigned* __restrict__ bar,
                                                float* __restrict__ out) {
    __shared__ float Glds[16][68];

    int tid = threadIdx.x;
    int w = tid >> 6, l = tid & 63;
    int lr = l & 15, lk = l >> 4;
    int g4 = blockIdx.x * 4;

    // preload W_hh fragments: lane lr -> n_local = q*4+u, gate row q*1024+g4+u
    int q = lr >> 2, u = lr & 3;
    long nrow = (long)(q * 1024 + g4 + u) * 1024;
    bf16x8 wf[32];
#pragma unroll
    for (int kk = 0; kk < 32; ++kk) {
        int k0 = kk * 32 + lk * 8;
        float4 w0 = *(const float4*)(Whh + nrow + k0);
        float4 w1 = *(const float4*)(Whh + nrow + k0 + 4);
        wf[kk] = pack8(w0, w1);
    }

    float c = 0.0f;
    unsigned short* h0 = hbuf;
    unsigned short* h1 = hbuf + NBATCH * HID;
    unsigned* cnt = bar;
    unsigned* gen = bar + 1;

    for (int t = 0; t < SEQ; ++t) {
        unsigned short* hc = (t & 1) ? h1 : h0;
        unsigned short* hn = (t & 1) ? h0 : h1;

        // MFMA phase: wave w computes batches [w*16, w*16+16) x 16 gate cols
        f32x4 acc0 = {0.f, 0.f, 0.f, 0.f}, acc1 = {0.f, 0.f, 0.f, 0.f};
        const unsigned short* hrow = hc + (w * 16 + lr) * HID + lk * 8;
#pragma unroll
        for (int kk = 0; kk < 32; kk += 2) {
            bf16x8 a0 = *(const bf16x8*)(hrow + kk * 32);
            bf16x8 a1 = *(const bf16x8*)(hrow + kk * 32 + 32);
            acc0 = __builtin_amdgcn_mfma_f32_16x16x32_bf16(a0, wf[kk],     acc0, 0, 0, 0);
            acc1 = __builtin_amdgcn_mfma_f32_16x16x32_bf16(a1, wf[kk + 1], acc1, 0, 0, 0);
        }
        f32x4 gacc = acc0 + acc1;
        // D: lane holds rows lk*4+r, col lr -> Glds[lr][w*16 + lk*4 + r]
        *(f32x4*)&Glds[lr][w * 16 + lk * 4] = gacc;
        __syncthreads();

        // activation: thread owns batch b=l, hidden unit g4+w
        float p[4];
#pragma unroll
        for (int qq = 0; qq < 4; ++qq)
            p[qq] = Glds[qq * 4 + w][l] +
                    XW[(long)t * (NGATE * 64) + (long)(qq * 1024 + g4 + w) * 64 + l];
        float ig = sigmoidf_(p[0]);
        float fg = sigmoidf_(p[1]);
        float gg = tanhf_(p[2]);
        float og = sigmoidf_(p[3]);
        c = fg * c + ig * gg;
        float h = og * tanhf_(c);
        hn[l * HID + g4 + w] = f2bf(h);
        if (t == SEQ - 1) {
            out[l * HID + g4 + w] = h;
            out[NBATCH * HID + l * HID + g4 + w] = c;
        } else {
            gbar(cnt, gen);   // h visible to all; also fences Glds for next iter
        }
    }
}

// ---- launch ------------------------------------------------------------
extern "C" void kernel_launch(void* const* d_in, const int* in_sizes, int n_in,
                              void* d_out, int out_size, void* d_ws, size_t ws_size,
                              hipStream_t stream) {
    const float* emb  = (const float*)d_in[0];
    const float* W_ih = (const float*)d_in[1];
    const float* W_hh = (const float*)d_in[2];
    const float* b_ih = (const float*)d_in[3];
    const float* b_hh = (const float*)d_in[4];
    const int*   inp  = (const int*)d_in[5];
    float* out = (float*)d_out;

    // workspace layout (~152.3 MiB used)
    char* ws = (char*)d_ws;
    float*          XW   = (float*)ws;                            // 134,217,728 B
    unsigned short* Xbf  = (unsigned short*)(ws + 134217728);     //  16,777,216 B
    unsigned short* Wbf  = (unsigned short*)(ws + 150994944);     //   8,388,608 B
    float*          bs   = (float*)(ws + 159383552);              //      16,384 B
    unsigned short* hbuf = (unsigned short*)(ws + 159399936);     //     262,144 B
    unsigned*       bar  = (unsigned*)(ws + 159662080);           //           8 B

    hipMemsetAsync(hbuf, 0, NBATCH * HID * sizeof(unsigned short), stream);
    hipMemsetAsync(bar, 0, 2 * sizeof(unsigned), stream);
    gather_x<<<SEQ * NBATCH, 256, 0, stream>>>(emb, inp, Xbf);
    conv_w<<<NGATE, 256, 0, stream>>>(W_ih, Wbf);
    bsum_k<<<16, 256, 0, stream>>>(b_ih, b_hh, bs);
    gemm_xw<<<dim3(32, 64), 256, 0, stream>>>(Xbf, Wbf, bs, XW);
    lstm_rec<<<NBLK, 256, 0, stream>>>(W_hh, XW, hbuf, bar, out);
}

// Round 3
// 4182.502 us; speedup vs baseline: 1.1234x; 1.1234x over previous
//
#include <hip/hip_runtime.h>
#include <hip/hip_bf16.h>

#define EMB   1024
#define HID   1024
#define NBATCH 64
#define SEQ   128
#define NGATE 4096   // 4*HID
#define NBLK  256    // recurrence grid

typedef __attribute__((ext_vector_type(8))) short bf16x8;
typedef __attribute__((ext_vector_type(4))) float f32x4;

__device__ __forceinline__ unsigned short f2bf(float f) {
    unsigned int u = __float_as_uint(f);
    unsigned int r = (u + 0x7FFFu + ((u >> 16) & 1u)) >> 16;
    return (unsigned short)r;
}

__device__ __forceinline__ bf16x8 pack8(float4 a, float4 b) {
    bf16x8 r;
    r[0] = (short)f2bf(a.x); r[1] = (short)f2bf(a.y);
    r[2] = (short)f2bf(a.z); r[3] = (short)f2bf(a.w);
    r[4] = (short)f2bf(b.x); r[5] = (short)f2bf(b.y);
    r[6] = (short)f2bf(b.z); r[7] = (short)f2bf(b.w);
    return r;
}

__device__ __forceinline__ float sigmoidf_(float x) { return 1.0f / (1.0f + __expf(-x)); }
__device__ __forceinline__ float tanhf_(float x)    { return 1.0f - 2.0f / (1.0f + __expf(2.0f * x)); }

// ---- prep kernels ------------------------------------------------------

// X[t*64+b][k] = bf16(emb[inputs[b][t]][k]);  grid 8192, block 256
__global__ void gather_x(const float* __restrict__ emb, const int* __restrict__ inp,
                         unsigned short* __restrict__ xbf) {
    int m = blockIdx.x;          // m = t*64 + b
    int t = m >> 6, b = m & 63;
    int tok = inp[b * SEQ + t];
    float4 v = ((const float4*)(emb + (long)tok * EMB))[threadIdx.x];
    ushort4 o;
    o.x = f2bf(v.x); o.y = f2bf(v.y); o.z = f2bf(v.z); o.w = f2bf(v.w);
    ((ushort4*)(xbf + (long)m * EMB))[threadIdx.x] = o;
}

// W_ih -> bf16; grid 4096, block 256
__global__ void conv_w(const float* __restrict__ w, unsigned short* __restrict__ wbf) {
    long i = (long)blockIdx.x * 1024 + (long)threadIdx.x * 4;
    float4 v = *(const float4*)(w + i);
    ushort4 o;
    o.x = f2bf(v.x); o.y = f2bf(v.y); o.z = f2bf(v.z); o.w = f2bf(v.w);
    *(ushort4*)(wbf + i) = o;
}

// bsum = b_ih + b_hh; grid 16, block 256
__global__ void bsum_k(const float* __restrict__ bi, const float* __restrict__ bh,
                       float* __restrict__ bs) {
    int i = blockIdx.x * 256 + threadIdx.x;
    bs[i] = bi[i] + bh[i];
}

// ---- input GEMM: XW[t][n][b] = sum_k X[t*64+b][k]*W_ih[n][k] + bsum[n] ----
__global__ __launch_bounds__(256) void gemm_xw(const unsigned short* __restrict__ A,
                                               const unsigned short* __restrict__ Bw,
                                               const float* __restrict__ bsum,
                                               float* __restrict__ XW) {
    __shared__ unsigned short As[128][40];
    __shared__ unsigned short Bs[128][40];
    int bx = blockIdx.x;             // N tile (0..31)
    int by = blockIdx.y;             // M tile (0..63)
    int tid = threadIdx.x;
    int w = tid >> 6, l = tid & 63;
    int wm = w >> 1, wn = w & 1;
    int lr = l & 15, lk = l >> 4;

    f32x4 acc[4][4];
#pragma unroll
    for (int ni = 0; ni < 4; ++ni) {
        float bsv = bsum[bx * 128 + wn * 64 + ni * 16 + lr];
#pragma unroll
        for (int mi = 0; mi < 4; ++mi) {
            acc[mi][ni][0] = bsv; acc[mi][ni][1] = bsv;
            acc[mi][ni][2] = bsv; acc[mi][ni][3] = bsv;
        }
    }

    int sr = tid >> 1;
    int sc = (tid & 1) * 16;
    const unsigned short* ga = A  + (long)(by * 128 + sr) * 1024 + sc;
    const unsigned short* gb = Bw + (long)(bx * 128 + sr) * 1024 + sc;

    for (int kt = 0; kt < 32; ++kt) {
        uint4 va0 = *(const uint4*)(ga);
        uint4 va1 = *(const uint4*)(ga + 8);
        uint4 vb0 = *(const uint4*)(gb);
        uint4 vb1 = *(const uint4*)(gb + 8);
        *(uint4*)&As[sr][sc]     = va0;
        *(uint4*)&As[sr][sc + 8] = va1;
        *(uint4*)&Bs[sr][sc]     = vb0;
        *(uint4*)&Bs[sr][sc + 8] = vb1;
        __syncthreads();

        bf16x8 af[4], bfr[4];
#pragma unroll
        for (int mi = 0; mi < 4; ++mi)
            af[mi] = *(const bf16x8*)&As[wm * 64 + mi * 16 + lr][lk * 8];
#pragma unroll
        for (int ni = 0; ni < 4; ++ni)
            bfr[ni] = *(const bf16x8*)&Bs[wn * 64 + ni * 16 + lr][lk * 8];
#pragma unroll
        for (int mi = 0; mi < 4; ++mi)
#pragma unroll
            for (int ni = 0; ni < 4; ++ni)
                acc[mi][ni] = __builtin_amdgcn_mfma_f32_16x16x32_bf16(af[mi], bfr[ni], acc[mi][ni], 0, 0, 0);
        __syncthreads();
        ga += 32; gb += 32;
    }

#pragma unroll
    for (int mi = 0; mi < 4; ++mi) {
        int mg = by * 128 + wm * 64 + mi * 16 + lk * 4;
        int tt = mg >> 6;
        int bb = mg & 63;
#pragma unroll
        for (int ni = 0; ni < 4; ++ni) {
            int nn = bx * 128 + wn * 64 + ni * 16 + lr;
            *(f32x4*)(XW + (long)tt * (NGATE * 64) + (long)nn * 64 + bb) = acc[mi][ni];
        }
    }
}

// ---- recurrence (normal launch + flag-array grid barrier) --------------
// 256 WGs x 256 thr. WG g owns hidden units g*4..g*4+3 (16 gate rows).
// W_hh frags live in registers (32 x bf16x8). h ping-pongs via bf16 global buf.
// Barrier: block b stores flags[b]=t+1 (distinct addresses -> no RMW
// serialization); thread tid polls flags[tid]; __syncthreads() joins.
__global__ __launch_bounds__(256) void lstm_rec(const float* __restrict__ Whh,
                                                const float* __restrict__ XW,
                                                unsigned short* __restrict__ hbuf,
                                                unsigned* __restrict__ flags,
                                                float* __restrict__ out) {
    __shared__ float Glds[16][68];

    int tid = threadIdx.x;
    int w = tid >> 6, l = tid & 63;
    int lr = l & 15, lk = l >> 4;
    int g4 = blockIdx.x * 4;

    // preload W_hh fragments: lane lr -> n_local = q*4+u, gate row q*1024+g4+u
    int q = lr >> 2, u = lr & 3;
    long nrow = (long)(q * 1024 + g4 + u) * 1024;
    bf16x8 wf[32];
#pragma unroll
    for (int kk = 0; kk < 32; ++kk) {
        int k0 = kk * 32 + lk * 8;
        float4 w0 = *(const float4*)(Whh + nrow + k0);
        float4 w1 = *(const float4*)(Whh + nrow + k0 + 4);
        wf[kk] = pack8(w0, w1);
    }

    float c = 0.0f;
    unsigned short* h0 = hbuf;
    unsigned short* h1 = hbuf + NBATCH * HID;

    for (int t = 0; t < SEQ; ++t) {
        unsigned short* hc = (t & 1) ? h1 : h0;
        unsigned short* hn = (t & 1) ? h0 : h1;

        // prefetch this step's XW gate values (read-only, hides under MFMA)
        float px[4];
#pragma unroll
        for (int qq = 0; qq < 4; ++qq)
            px[qq] = XW[(long)t * (NGATE * 64) + (long)(qq * 1024 + g4 + w) * 64 + l];

        // MFMA phase: wave w computes batches [w*16, w*16+16) x 16 gate cols
        f32x4 acc0 = {0.f, 0.f, 0.f, 0.f}, acc1 = {0.f, 0.f, 0.f, 0.f};
        const unsigned short* hrow = hc + (w * 16 + lr) * HID + lk * 8;
#pragma unroll
        for (int kk = 0; kk < 32; kk += 2) {
            bf16x8 a0 = *(const bf16x8*)(hrow + kk * 32);
            bf16x8 a1 = *(const bf16x8*)(hrow + kk * 32 + 32);
            acc0 = __builtin_amdgcn_mfma_f32_16x16x32_bf16(a0, wf[kk],     acc0, 0, 0, 0);
            acc1 = __builtin_amdgcn_mfma_f32_16x16x32_bf16(a1, wf[kk + 1], acc1, 0, 0, 0);
        }
        f32x4 gacc = acc0 + acc1;
        // D: lane holds rows lk*4+r, col lr -> Glds[lr][w*16 + lk*4 + r]
        *(f32x4*)&Glds[lr][w * 16 + lk * 4] = gacc;
        __syncthreads();

        // activation: thread owns batch b=l, hidden unit g4+w
        float p[4];
#pragma unroll
        for (int qq = 0; qq < 4; ++qq)
            p[qq] = Glds[qq * 4 + w][l] + px[qq];
        float ig = sigmoidf_(p[0]);
        float fg = sigmoidf_(p[1]);
        float gg = tanhf_(p[2]);
        float og = sigmoidf_(p[3]);
        c = fg * c + ig * gg;
        float h = og * tanhf_(c);
        hn[l * HID + g4 + w] = f2bf(h);
        if (t == SEQ - 1) {
            out[l * HID + g4 + w] = h;
            out[NBATCH * HID + l * HID + g4 + w] = c;
        } else {
            // ---- flag-array grid barrier ----
            __syncthreads();                       // all h-stores of block issued
            if (tid == 0) {
                __threadfence();                   // release: h visible before flag
                __hip_atomic_store(&flags[blockIdx.x], (unsigned)(t + 1),
                                   __ATOMIC_RELAXED, __HIP_MEMORY_SCOPE_AGENT);
            }
            unsigned tv = (unsigned)(t + 1);
            long spins = 0;
            while (__hip_atomic_load(&flags[tid], __ATOMIC_RELAXED,
                                     __HIP_MEMORY_SCOPE_AGENT) < tv &&
                   spins < 2000000L) {
                __builtin_amdgcn_s_sleep(1);
                ++spins;
            }
            __threadfence();                       // acquire: see peers' h
            __syncthreads();
        }
    }
}

// ---- launch ------------------------------------------------------------
extern "C" void kernel_launch(void* const* d_in, const int* in_sizes, int n_in,
                              void* d_out, int out_size, void* d_ws, size_t ws_size,
                              hipStream_t stream) {
    const float* emb  = (const float*)d_in[0];
    const float* W_ih = (const float*)d_in[1];
    const float* W_hh = (const float*)d_in[2];
    const float* b_ih = (const float*)d_in[3];
    const float* b_hh = (const float*)d_in[4];
    const int*   inp  = (const int*)d_in[5];
    float* out = (float*)d_out;

    // workspace layout (~152.3 MiB used)
    char* ws = (char*)d_ws;
    float*          XW   = (float*)ws;                            // 134,217,728 B
    unsigned short* Xbf  = (unsigned short*)(ws + 134217728);     //  16,777,216 B
    unsigned short* Wbf  = (unsigned short*)(ws + 150994944);     //   8,388,608 B
    float*          bs   = (float*)(ws + 159383552);              //      16,384 B
    unsigned short* hbuf = (unsigned short*)(ws + 159399936);     //     262,144 B
    unsigned*       flags= (unsigned*)(ws + 159662080);           //       1,024 B

    hipMemsetAsync(hbuf, 0, NBATCH * HID * sizeof(unsigned short), stream);
    hipMemsetAsync(flags, 0, NBLK * sizeof(unsigned), stream);
    gather_x<<<SEQ * NBATCH, 256, 0, stream>>>(emb, inp, Xbf);
    conv_w<<<NGATE, 256, 0, stream>>>(W_ih, Wbf);
    bsum_k<<<16, 256, 0, stream>>>(b_ih, b_hh, bs);
    gemm_xw<<<dim3(32, 64), 256, 0, stream>>>(Xbf, Wbf, bs, XW);
    lstm_rec<<<NBLK, 256, 0, stream>>>(W_hh, XW, hbuf, flags, out);
}

// Round 4
// 1998.460 us; speedup vs baseline: 2.3511x; 2.0929x over previous
//
#include <hip/hip_runtime.h>
#include <hip/hip_bf16.h>

#define EMB   1024
#define HID   1024
#define NBATCH 64
#define SEQ   128
#define NGATE 4096   // 4*HID
#define NBLK  256    // recurrence grid

typedef __attribute__((ext_vector_type(8))) short bf16x8;
typedef __attribute__((ext_vector_type(4))) float f32x4;

__device__ __forceinline__ unsigned short f2bf(float f) {
    unsigned int u = __float_as_uint(f);
    unsigned int r = (u + 0x7FFFu + ((u >> 16) & 1u)) >> 16;
    return (unsigned short)r;
}

__device__ __forceinline__ bf16x8 pack8(float4 a, float4 b) {
    bf16x8 r;
    r[0] = (short)f2bf(a.x); r[1] = (short)f2bf(a.y);
    r[2] = (short)f2bf(a.z); r[3] = (short)f2bf(a.w);
    r[4] = (short)f2bf(b.x); r[5] = (short)f2bf(b.y);
    r[6] = (short)f2bf(b.z); r[7] = (short)f2bf(b.w);
    return r;
}

__device__ __forceinline__ float sigmoidf_(float x) { return 1.0f / (1.0f + __expf(-x)); }
__device__ __forceinline__ float tanhf_(float x)    { return 1.0f - 2.0f / (1.0f + __expf(2.0f * x)); }

// ---- prep kernels ------------------------------------------------------

// X[t*64+b][k] = bf16(emb[inputs[b][t]][k]);  grid 8192, block 256
__global__ void gather_x(const float* __restrict__ emb, const int* __restrict__ inp,
                         unsigned short* __restrict__ xbf) {
    int m = blockIdx.x;          // m = t*64 + b
    int t = m >> 6, b = m & 63;
    int tok = inp[b * SEQ + t];
    float4 v = ((const float4*)(emb + (long)tok * EMB))[threadIdx.x];
    ushort4 o;
    o.x = f2bf(v.x); o.y = f2bf(v.y); o.z = f2bf(v.z); o.w = f2bf(v.w);
    ((ushort4*)(xbf + (long)m * EMB))[threadIdx.x] = o;
}

// W_ih -> bf16; grid 4096, block 256
__global__ void conv_w(const float* __restrict__ w, unsigned short* __restrict__ wbf) {
    long i = (long)blockIdx.x * 1024 + (long)threadIdx.x * 4;
    float4 v = *(const float4*)(w + i);
    ushort4 o;
    o.x = f2bf(v.x); o.y = f2bf(v.y); o.z = f2bf(v.z); o.w = f2bf(v.w);
    *(ushort4*)(wbf + i) = o;
}

// bsum = b_ih + b_hh; grid 16, block 256
__global__ void bsum_k(const float* __restrict__ bi, const float* __restrict__ bh,
                       float* __restrict__ bs) {
    int i = blockIdx.x * 256 + threadIdx.x;
    bs[i] = bi[i] + bh[i];
}

// ---- input GEMM: XW[t][n][b] = sum_k X[t*64+b][k]*W_ih[n][k] + bsum[n] ----
__global__ __launch_bounds__(256) void gemm_xw(const unsigned short* __restrict__ A,
                                               const unsigned short* __restrict__ Bw,
                                               const float* __restrict__ bsum,
                                               float* __restrict__ XW) {
    __shared__ unsigned short As[128][40];
    __shared__ unsigned short Bs[128][40];
    int bx = blockIdx.x;             // N tile (0..31)
    int by = blockIdx.y;             // M tile (0..63)
    int tid = threadIdx.x;
    int w = tid >> 6, l = tid & 63;
    int wm = w >> 1, wn = w & 1;
    int lr = l & 15, lk = l >> 4;

    f32x4 acc[4][4];
#pragma unroll
    for (int ni = 0; ni < 4; ++ni) {
        float bsv = bsum[bx * 128 + wn * 64 + ni * 16 + lr];
#pragma unroll
        for (int mi = 0; mi < 4; ++mi) {
            acc[mi][ni][0] = bsv; acc[mi][ni][1] = bsv;
            acc[mi][ni][2] = bsv; acc[mi][ni][3] = bsv;
        }
    }

    int sr = tid >> 1;
    int sc = (tid & 1) * 16;
    const unsigned short* ga = A  + (long)(by * 128 + sr) * 1024 + sc;
    const unsigned short* gb = Bw + (long)(bx * 128 + sr) * 1024 + sc;

    for (int kt = 0; kt < 32; ++kt) {
        uint4 va0 = *(const uint4*)(ga);
        uint4 va1 = *(const uint4*)(ga + 8);
        uint4 vb0 = *(const uint4*)(gb);
        uint4 vb1 = *(const uint4*)(gb + 8);
        *(uint4*)&As[sr][sc]     = va0;
        *(uint4*)&As[sr][sc + 8] = va1;
        *(uint4*)&Bs[sr][sc]     = vb0;
        *(uint4*)&Bs[sr][sc + 8] = vb1;
        __syncthreads();

        bf16x8 af[4], bfr[4];
#pragma unroll
        for (int mi = 0; mi < 4; ++mi)
            af[mi] = *(const bf16x8*)&As[wm * 64 + mi * 16 + lr][lk * 8];
#pragma unroll
        for (int ni = 0; ni < 4; ++ni)
            bfr[ni] = *(const bf16x8*)&Bs[wn * 64 + ni * 16 + lr][lk * 8];
#pragma unroll
        for (int mi = 0; mi < 4; ++mi)
#pragma unroll
            for (int ni = 0; ni < 4; ++ni)
                acc[mi][ni] = __builtin_amdgcn_mfma_f32_16x16x32_bf16(af[mi], bfr[ni], acc[mi][ni], 0, 0, 0);
        __syncthreads();
        ga += 32; gb += 32;
    }

#pragma unroll
    for (int mi = 0; mi < 4; ++mi) {
        int mg = by * 128 + wm * 64 + mi * 16 + lk * 4;
        int tt = mg >> 6;
        int bb = mg & 63;
#pragma unroll
        for (int ni = 0; ni < 4; ++ni) {
            int nn = bx * 128 + wn * 64 + ni * 16 + lr;
            *(f32x4*)(XW + (long)tt * (NGATE * 64) + (long)nn * 64 + bb) = acc[mi][ni];
        }
    }
}

// ---- recurrence: flush-free cross-XCD exchange -------------------------
// 256 WGs x 256 thr. WG g owns hidden units g*4..g*4+3 (16 gate rows).
// W_hh frags in registers. h ping-pongs via AGENT-SCOPE (sc1) loads/stores:
// these bypass the non-coherent per-XCD L2 and hit the coherence point, so
// NO buffer_wbl2/buffer_inv fences are needed anywhere in the loop.
// Ordering: h-stores drained per-thread (s_waitcnt vmcnt(0)) before
// __syncthreads; tid0 then publishes flags[block]=t+1; all threads poll.
__global__ __launch_bounds__(256) void lstm_rec(const float* __restrict__ Whh,
                                                const float* __restrict__ XW,
                                                unsigned short* __restrict__ hbuf,
                                                unsigned* __restrict__ flags,
                                                float* __restrict__ out) {
    __shared__ float Glds[16][68];

    int tid = threadIdx.x;
    int w = tid >> 6, l = tid & 63;
    int lr = l & 15, lk = l >> 4;
    int g4 = blockIdx.x * 4;

    // preload W_hh fragments: lane lr -> n_local = q*4+u, gate row q*1024+g4+u
    int q = lr >> 2, u = lr & 3;
    long nrow = (long)(q * 1024 + g4 + u) * 1024;
    bf16x8 wf[32];
#pragma unroll
    for (int kk = 0; kk < 32; ++kk) {
        int k0 = kk * 32 + lk * 8;
        float4 w0 = *(const float4*)(Whh + nrow + k0);
        float4 w1 = *(const float4*)(Whh + nrow + k0 + 4);
        wf[kk] = pack8(w0, w1);
    }

    float c = 0.0f;
    unsigned long long* h0 = (unsigned long long*)hbuf;
    unsigned long long* h1 = (unsigned long long*)(hbuf + NBATCH * HID);

    for (int t = 0; t < SEQ; ++t) {
        const unsigned long long* hc = (t & 1) ? h1 : h0;
        unsigned short* hn = (unsigned short*)((t & 1) ? h0 : h1);

        // prefetch this step's XW gate values (plain cached loads)
        float px[4];
#pragma unroll
        for (int qq = 0; qq < 4; ++qq)
            px[qq] = XW[(long)t * (NGATE * 64) + (long)(qq * 1024 + g4 + w) * 64 + l];

        // MFMA phase: wave w computes batches [w*16, w*16+16) x 16 gate cols
        // h read with agent-scope 8B loads (sc1: bypass L1/L2, coherent).
        f32x4 acc0 = {0.f, 0.f, 0.f, 0.f}, acc1 = {0.f, 0.f, 0.f, 0.f};
        const unsigned long long* hq =
            hc + (((long)(w * 16 + lr)) * HID + lk * 8) / 4;   // 4 bf16 per ULL
#pragma unroll
        for (int kk = 0; kk < 32; kk += 2) {
            union { unsigned long long qv[2]; bf16x8 v; } ua, ub;
            ua.qv[0] = __hip_atomic_load(hq + kk * 8,     __ATOMIC_RELAXED, __HIP_MEMORY_SCOPE_AGENT);
            ua.qv[1] = __hip_atomic_load(hq + kk * 8 + 1, __ATOMIC_RELAXED, __HIP_MEMORY_SCOPE_AGENT);
            ub.qv[0] = __hip_atomic_load(hq + kk * 8 + 8, __ATOMIC_RELAXED, __HIP_MEMORY_SCOPE_AGENT);
            ub.qv[1] = __hip_atomic_load(hq + kk * 8 + 9, __ATOMIC_RELAXED, __HIP_MEMORY_SCOPE_AGENT);
            acc0 = __builtin_amdgcn_mfma_f32_16x16x32_bf16(ua.v, wf[kk],     acc0, 0, 0, 0);
            acc1 = __builtin_amdgcn_mfma_f32_16x16x32_bf16(ub.v, wf[kk + 1], acc1, 0, 0, 0);
        }
        f32x4 gacc = acc0 + acc1;
        // D: lane holds rows lk*4+r, col lr -> Glds[lr][w*16 + lk*4 + r]
        *(f32x4*)&Glds[lr][w * 16 + lk * 4] = gacc;
        __syncthreads();

        // activation: thread owns batch b=l, hidden unit g4+w
        float p[4];
#pragma unroll
        for (int qq = 0; qq < 4; ++qq)
            p[qq] = Glds[qq * 4 + w][l] + px[qq];
        float ig = sigmoidf_(p[0]);
        float fg = sigmoidf_(p[1]);
        float gg = tanhf_(p[2]);
        float og = sigmoidf_(p[3]);
        c = fg * c + ig * gg;
        float h = og * tanhf_(c);

        if (t == SEQ - 1) {
            out[l * HID + g4 + w] = h;
            out[NBATCH * HID + l * HID + g4 + w] = c;
        } else {
            // h store: agent-scope write-through (visible at coherence point)
            __hip_atomic_store(&hn[l * HID + g4 + w], f2bf(h),
                               __ATOMIC_RELAXED, __HIP_MEMORY_SCOPE_AGENT);
            // drain my stores (ack from coherence point), no cache flush
            asm volatile("s_waitcnt vmcnt(0)" ::: "memory");
            __syncthreads();            // all threads' h-stores drained
            if (tid == 0)
                __hip_atomic_store(&flags[blockIdx.x], (unsigned)(t + 1),
                                   __ATOMIC_RELAXED, __HIP_MEMORY_SCOPE_AGENT);
            unsigned tv = (unsigned)(t + 1);
            long spins = 0;
            while (__hip_atomic_load(&flags[tid], __ATOMIC_RELAXED,
                                     __HIP_MEMORY_SCOPE_AGENT) < tv &&
                   spins < 2000000L) {
                __builtin_amdgcn_s_sleep(1);
                ++spins;
            }
            __syncthreads();            // whole block saw all flags
        }
    }
}

// ---- launch ------------------------------------------------------------
extern "C" void kernel_launch(void* const* d_in, const int* in_sizes, int n_in,
                              void* d_out, int out_size, void* d_ws, size_t ws_size,
                              hipStream_t stream) {
    const float* emb  = (const float*)d_in[0];
    const float* W_ih = (const float*)d_in[1];
    const float* W_hh = (const float*)d_in[2];
    const float* b_ih = (const float*)d_in[3];
    const float* b_hh = (const float*)d_in[4];
    const int*   inp  = (const int*)d_in[5];
    float* out = (float*)d_out;

    // workspace layout (~152.3 MiB used)
    char* ws = (char*)d_ws;
    float*          XW   = (float*)ws;                            // 134,217,728 B
    unsigned short* Xbf  = (unsigned short*)(ws + 134217728);     //  16,777,216 B
    unsigned short* Wbf  = (unsigned short*)(ws + 150994944);     //   8,388,608 B
    float*          bs   = (float*)(ws + 159383552);              //      16,384 B
    unsigned short* hbuf = (unsigned short*)(ws + 159399936);     //     262,144 B
    unsigned*       flags= (unsigned*)(ws + 159662080);           //       1,024 B

    hipMemsetAsync(hbuf, 0, NBATCH * HID * sizeof(unsigned short), stream);
    hipMemsetAsync(flags, 0, NBLK * sizeof(unsigned), stream);
    gather_x<<<SEQ * NBATCH, 256, 0, stream>>>(emb, inp, Xbf);
    conv_w<<<NGATE, 256, 0, stream>>>(W_ih, Wbf);
    bsum_k<<<16, 256, 0, stream>>>(b_ih, b_hh, bs);
    gemm_xw<<<dim3(32, 64), 256, 0, stream>>>(Xbf, Wbf, bs, XW);
    lstm_rec<<<NBLK, 256, 0, stream>>>(W_hh, XW, hbuf, flags, out);
}

// Round 5
// 1123.465 us; speedup vs baseline: 4.1822x; 1.7788x over previous
//
#include <hip/hip_runtime.h>
#include <hip/hip_bf16.h>

#define EMB   1024
#define HID   1024
#define NBATCH 64
#define SEQ   128
#define NGATE 4096   // 4*HID
#define NBLK  256    // recurrence grid

typedef __attribute__((ext_vector_type(8))) short bf16x8;
typedef __attribute__((ext_vector_type(4))) float f32x4;

__device__ __forceinline__ unsigned short f2bf(float f) {
    unsigned int u = __float_as_uint(f);
    unsigned int r = (u + 0x7FFFu + ((u >> 16) & 1u)) >> 16;
    return (unsigned short)r;
}

__device__ __forceinline__ bf16x8 pack8(float4 a, float4 b) {
    bf16x8 r;
    r[0] = (short)f2bf(a.x); r[1] = (short)f2bf(a.y);
    r[2] = (short)f2bf(a.z); r[3] = (short)f2bf(a.w);
    r[4] = (short)f2bf(b.x); r[5] = (short)f2bf(b.y);
    r[6] = (short)f2bf(b.z); r[7] = (short)f2bf(b.w);
    return r;
}

__device__ __forceinline__ float sigmoidf_(float x) { return 1.0f / (1.0f + __expf(-x)); }
__device__ __forceinline__ float tanhf_(float x)    { return 1.0f - 2.0f / (1.0f + __expf(2.0f * x)); }

// ---- prep kernels ------------------------------------------------------

// X[t*64+b][k] = bf16(emb[inputs[b][t]][k]);  grid 8192, block 256
__global__ void gather_x(const float* __restrict__ emb, const int* __restrict__ inp,
                         unsigned short* __restrict__ xbf) {
    int m = blockIdx.x;          // m = t*64 + b
    int t = m >> 6, b = m & 63;
    int tok = inp[b * SEQ + t];
    float4 v = ((const float4*)(emb + (long)tok * EMB))[threadIdx.x];
    ushort4 o;
    o.x = f2bf(v.x); o.y = f2bf(v.y); o.z = f2bf(v.z); o.w = f2bf(v.w);
    ((ushort4*)(xbf + (long)m * EMB))[threadIdx.x] = o;
}

// W_ih -> bf16; grid 4096, block 256
__global__ void conv_w(const float* __restrict__ w, unsigned short* __restrict__ wbf) {
    long i = (long)blockIdx.x * 1024 + (long)threadIdx.x * 4;
    float4 v = *(const float4*)(w + i);
    ushort4 o;
    o.x = f2bf(v.x); o.y = f2bf(v.y); o.z = f2bf(v.z); o.w = f2bf(v.w);
    *(ushort4*)(wbf + i) = o;
}

// bsum = b_ih + b_hh; grid 16, block 256
__global__ void bsum_k(const float* __restrict__ bi, const float* __restrict__ bh,
                       float* __restrict__ bs) {
    int i = blockIdx.x * 256 + threadIdx.x;
    bs[i] = bi[i] + bh[i];
}

// ---- input GEMM: XW[t][n][b] = sum_k X[t*64+b][k]*W_ih[n][k] + bsum[n] ----
__global__ __launch_bounds__(256) void gemm_xw(const unsigned short* __restrict__ A,
                                               const unsigned short* __restrict__ Bw,
                                               const float* __restrict__ bsum,
                                               float* __restrict__ XW) {
    __shared__ unsigned short As[128][40];
    __shared__ unsigned short Bs[128][40];
    int bx = blockIdx.x;             // N tile (0..31)
    int by = blockIdx.y;             // M tile (0..63)
    int tid = threadIdx.x;
    int w = tid >> 6, l = tid & 63;
    int wm = w >> 1, wn = w & 1;
    int lr = l & 15, lk = l >> 4;

    f32x4 acc[4][4];
#pragma unroll
    for (int ni = 0; ni < 4; ++ni) {
        float bsv = bsum[bx * 128 + wn * 64 + ni * 16 + lr];
#pragma unroll
        for (int mi = 0; mi < 4; ++mi) {
            acc[mi][ni][0] = bsv; acc[mi][ni][1] = bsv;
            acc[mi][ni][2] = bsv; acc[mi][ni][3] = bsv;
        }
    }

    int sr = tid >> 1;
    int sc = (tid & 1) * 16;
    const unsigned short* ga = A  + (long)(by * 128 + sr) * 1024 + sc;
    const unsigned short* gb = Bw + (long)(bx * 128 + sr) * 1024 + sc;

    for (int kt = 0; kt < 32; ++kt) {
        uint4 va0 = *(const uint4*)(ga);
        uint4 va1 = *(const uint4*)(ga + 8);
        uint4 vb0 = *(const uint4*)(gb);
        uint4 vb1 = *(const uint4*)(gb + 8);
        *(uint4*)&As[sr][sc]     = va0;
        *(uint4*)&As[sr][sc + 8] = va1;
        *(uint4*)&Bs[sr][sc]     = vb0;
        *(uint4*)&Bs[sr][sc + 8] = vb1;
        __syncthreads();

        bf16x8 af[4], bfr[4];
#pragma unroll
        for (int mi = 0; mi < 4; ++mi)
            af[mi] = *(const bf16x8*)&As[wm * 64 + mi * 16 + lr][lk * 8];
#pragma unroll
        for (int ni = 0; ni < 4; ++ni)
            bfr[ni] = *(const bf16x8*)&Bs[wn * 64 + ni * 16 + lr][lk * 8];
#pragma unroll
        for (int mi = 0; mi < 4; ++mi)
#pragma unroll
            for (int ni = 0; ni < 4; ++ni)
                acc[mi][ni] = __builtin_amdgcn_mfma_f32_16x16x32_bf16(af[mi], bfr[ni], acc[mi][ni], 0, 0, 0);
        __syncthreads();
        ga += 32; gb += 32;
    }

#pragma unroll
    for (int mi = 0; mi < 4; ++mi) {
        int mg = by * 128 + wm * 64 + mi * 16 + lk * 4;
        int tt = mg >> 6;
        int bb = mg & 63;
#pragma unroll
        for (int ni = 0; ni < 4; ++ni) {
            int nn = bx * 128 + wn * 64 + ni * 16 + lr;
            *(f32x4*)(XW + (long)tt * (NGATE * 64) + (long)nn * 64 + bb) = acc[mi][ni];
        }
    }
}

// ---- recurrence: fresh-slot h exchange, L2-broadcast reads -------------
// hseq[SEQ] slots, one per step; slot layout [g=hid/4][b][u=hid%4] bf16
// (block g's 256 values are 512B contiguous -> one coalesced wave store).
// Writes: agent-scope (write-through to MALL/coherence point), drained with
// vmcnt(0) before the flag publish. Reads: NORMAL CACHED loads — safe
// because each slot address is never read before its flag says it's
// written (fresh address per step; deterministic values across replays),
// so no stale line can exist. Per-XCD L2 then serves 32 blocks from one
// 128KB fill instead of 32MB/step of MALL-bypass reads.
__global__ __launch_bounds__(256) void lstm_rec(const float* __restrict__ Whh,
                                                const float* __restrict__ XW,
                                                unsigned short* __restrict__ hseq,
                                                unsigned* __restrict__ flags,
                                                float* __restrict__ out) {
    __shared__ float Glds[16][68];
    __shared__ unsigned long long Hs[64];   // pack buffer: Hs[b] = 4 bf16

    int tid = threadIdx.x;
    int w = tid >> 6, l = tid & 63;
    int lr = l & 15, lk = l >> 4;
    int g4 = blockIdx.x * 4;

    // preload W_hh fragments: lane lr -> n_local = q*4+u, gate row q*1024+g4+u
    int q = lr >> 2, u = lr & 3;
    long nrow = (long)(q * 1024 + g4 + u) * 1024;
    bf16x8 wf[32];
#pragma unroll
    for (int kk = 0; kk < 32; ++kk) {
        int k0 = kk * 32 + lk * 8;
        float4 w0 = *(const float4*)(Whh + nrow + k0);
        float4 w1 = *(const float4*)(Whh + nrow + k0 + 4);
        wf[kk] = pack8(w0, w1);
    }

    float c = 0.0f;
    int brow = w * 16 + lr;   // batch row this lane contributes to

    for (int t = 0; t < SEQ; ++t) {
        // slot t, ull view: index g*64 + b  (g in [0,256), b in [0,64))
        const unsigned long long* hc =
            (const unsigned long long*)hseq + (long)t * 8192 + brow;

        // prefetch this step's XW gate values (plain cached loads)
        float px[4];
#pragma unroll
        for (int qq = 0; qq < 4; ++qq)
            px[qq] = XW[(long)t * (NGATE * 64) + (long)(qq * 1024 + g4 + w) * 64 + l];

        // MFMA phase: wave w computes batches [w*16, w*16+16) x 16 gate cols
        // A-frag k-group kk: k0 = kk*32 + lk*8 -> g0 = kk*8 + lk*2
        f32x4 acc0 = {0.f, 0.f, 0.f, 0.f}, acc1 = {0.f, 0.f, 0.f, 0.f};
#pragma unroll
        for (int kk = 0; kk < 32; kk += 2) {
            int g0 = kk * 8 + lk * 2;
            union { unsigned long long qv[2]; bf16x8 v; } ua, ub;
            ua.qv[0] = hc[(long)g0 * 64];
            ua.qv[1] = hc[(long)(g0 + 1) * 64];
            ub.qv[0] = hc[(long)(g0 + 8) * 64];
            ub.qv[1] = hc[(long)(g0 + 9) * 64];
            acc0 = __builtin_amdgcn_mfma_f32_16x16x32_bf16(ua.v, wf[kk],     acc0, 0, 0, 0);
            acc1 = __builtin_amdgcn_mfma_f32_16x16x32_bf16(ub.v, wf[kk + 1], acc1, 0, 0, 0);
        }
        f32x4 gacc = acc0 + acc1;
        // D: lane holds rows lk*4+r, col lr -> Glds[lr][w*16 + lk*4 + r]
        *(f32x4*)&Glds[lr][w * 16 + lk * 4] = gacc;
        __syncthreads();

        // activation: thread owns batch b=l, hidden unit g4+w  (g=blockIdx, u=w)
        float p[4];
#pragma unroll
        for (int qq = 0; qq < 4; ++qq)
            p[qq] = Glds[qq * 4 + w][l] + px[qq];
        float ig = sigmoidf_(p[0]);
        float fg = sigmoidf_(p[1]);
        float gg = tanhf_(p[2]);
        float og = sigmoidf_(p[3]);
        c = fg * c + ig * gg;
        float h = og * tanhf_(c);

        if (t == SEQ - 1) {
            out[l * HID + g4 + w] = h;
            out[NBATCH * HID + l * HID + g4 + w] = c;
        } else {
            // pack h into LDS: Hs[b=l], halfword u=w
            ((unsigned short*)&Hs[l])[w] = f2bf(h);
            __syncthreads();
            if (tid < 64) {   // wave 0: one coalesced 512B agent-scope store
                unsigned long long* hn = (unsigned long long*)hseq +
                                         (long)(t + 1) * 8192 + blockIdx.x * 64;
                __hip_atomic_store(&hn[tid], Hs[tid],
                                   __ATOMIC_RELAXED, __HIP_MEMORY_SCOPE_AGENT);
                asm volatile("s_waitcnt vmcnt(0)" ::: "memory");   // store ack'd at MALL
                if (tid == 0)
                    __hip_atomic_store(&flags[blockIdx.x], (unsigned)(t + 1),
                                       __ATOMIC_RELAXED, __HIP_MEMORY_SCOPE_AGENT);
            }
            // poll: thread tid watches block tid's flag (bypass loads, always fresh)
            unsigned tv = (unsigned)(t + 1);
            long spins = 0;
            while (__hip_atomic_load(&flags[tid], __ATOMIC_RELAXED,
                                     __HIP_MEMORY_SCOPE_AGENT) < tv &&
                   spins < 2000000L) {
                __builtin_amdgcn_s_sleep(1);
                ++spins;
            }
            __syncthreads();            // block collectively saw all 256 flags
        }
    }
}

// ---- launch ------------------------------------------------------------
extern "C" void kernel_launch(void* const* d_in, const int* in_sizes, int n_in,
                              void* d_out, int out_size, void* d_ws, size_t ws_size,
                              hipStream_t stream) {
    const float* emb  = (const float*)d_in[0];
    const float* W_ih = (const float*)d_in[1];
    const float* W_hh = (const float*)d_in[2];
    const float* b_ih = (const float*)d_in[3];
    const float* b_hh = (const float*)d_in[4];
    const int*   inp  = (const int*)d_in[5];
    float* out = (float*)d_out;

    // workspace layout (~159.4 MiB used); hseq ALIASES Xbf (Xbf is dead
    // after gemm_xw completes; stream ordering makes the reuse safe).
    char* ws = (char*)d_ws;
    float*          XW   = (float*)ws;                            // 134,217,728 B
    unsigned short* Xbf  = (unsigned short*)(ws + 134217728);     //  16,777,216 B
    unsigned short* hseq = Xbf;                                   //  (alias, 128 slots x 128KB)
    unsigned short* Wbf  = (unsigned short*)(ws + 150994944);     //   8,388,608 B
    float*          bs   = (float*)(ws + 159383552);              //      16,384 B
    unsigned*       flags= (unsigned*)(ws + 159399936);           //       1,024 B

    hipMemsetAsync(flags, 0, NBLK * sizeof(unsigned), stream);
    gather_x<<<SEQ * NBATCH, 256, 0, stream>>>(emb, inp, Xbf);
    conv_w<<<NGATE, 256, 0, stream>>>(W_ih, Wbf);
    bsum_k<<<16, 256, 0, stream>>>(b_ih, b_hh, bs);
    gemm_xw<<<dim3(32, 64), 256, 0, stream>>>(Xbf, Wbf, bs, XW);
    // zero h slot 0 (after gemm_xw: hseq aliases Xbf)
    hipMemsetAsync(hseq, 0, NBATCH * HID * sizeof(unsigned short), stream);

    lstm_rec<<<NBLK, 256, 0, stream>>>(W_hh, XW, hseq, flags, out);
}

// Round 6
// 1101.546 us; speedup vs baseline: 4.2654x; 1.0199x over previous
//
#include <hip/hip_runtime.h>
#include <hip/hip_bf16.h>

#define EMB   1024
#define HID   1024
#define NBATCH 64
#define SEQ   128
#define NGATE 4096   // 4*HID
#define NBLK  256    // recurrence grid

typedef __attribute__((ext_vector_type(8))) short bf16x8;
typedef __attribute__((ext_vector_type(4))) float f32x4;

__device__ __forceinline__ unsigned short f2bf(float f) {
    unsigned int u = __float_as_uint(f);
    unsigned int r = (u + 0x7FFFu + ((u >> 16) & 1u)) >> 16;
    return (unsigned short)r;
}

__device__ __forceinline__ bf16x8 pack8(float4 a, float4 b) {
    bf16x8 r;
    r[0] = (short)f2bf(a.x); r[1] = (short)f2bf(a.y);
    r[2] = (short)f2bf(a.z); r[3] = (short)f2bf(a.w);
    r[4] = (short)f2bf(b.x); r[5] = (short)f2bf(b.y);
    r[6] = (short)f2bf(b.z); r[7] = (short)f2bf(b.w);
    return r;
}

__device__ __forceinline__ float sigmoidf_(float x) { return 1.0f / (1.0f + __expf(-x)); }
__device__ __forceinline__ float tanhf_(float x)    { return 1.0f - 2.0f / (1.0f + __expf(2.0f * x)); }

// ---- prep kernels ------------------------------------------------------

// X[t*64+b][k] = bf16(emb[inputs[b][t]][k]);  grid 8192, block 256
__global__ void gather_x(const float* __restrict__ emb, const int* __restrict__ inp,
                         unsigned short* __restrict__ xbf) {
    int m = blockIdx.x;          // m = t*64 + b
    int t = m >> 6, b = m & 63;
    int tok = inp[b * SEQ + t];
    float4 v = ((const float4*)(emb + (long)tok * EMB))[threadIdx.x];
    ushort4 o;
    o.x = f2bf(v.x); o.y = f2bf(v.y); o.z = f2bf(v.z); o.w = f2bf(v.w);
    ((ushort4*)(xbf + (long)m * EMB))[threadIdx.x] = o;
}

// W_ih -> bf16; grid 4096, block 256
__global__ void conv_w(const float* __restrict__ w, unsigned short* __restrict__ wbf) {
    long i = (long)blockIdx.x * 1024 + (long)threadIdx.x * 4;
    float4 v = *(const float4*)(w + i);
    ushort4 o;
    o.x = f2bf(v.x); o.y = f2bf(v.y); o.z = f2bf(v.z); o.w = f2bf(v.w);
    *(ushort4*)(wbf + i) = o;
}

// bsum = b_ih + b_hh; grid 16, block 256
__global__ void bsum_k(const float* __restrict__ bi, const float* __restrict__ bh,
                       float* __restrict__ bs) {
    int i = blockIdx.x * 256 + threadIdx.x;
    bs[i] = bi[i] + bh[i];
}

// ---- input GEMM: XW[t][n][b] = sum_k X[t*64+b][k]*W_ih[n][k] + bsum[n] ----
__global__ __launch_bounds__(256) void gemm_xw(const unsigned short* __restrict__ A,
                                               const unsigned short* __restrict__ Bw,
                                               const float* __restrict__ bsum,
                                               float* __restrict__ XW) {
    __shared__ unsigned short As[128][40];
    __shared__ unsigned short Bs[128][40];
    int bx = blockIdx.x;             // N tile (0..31)
    int by = blockIdx.y;             // M tile (0..63)
    int tid = threadIdx.x;
    int w = tid >> 6, l = tid & 63;
    int wm = w >> 1, wn = w & 1;
    int lr = l & 15, lk = l >> 4;

    f32x4 acc[4][4];
#pragma unroll
    for (int ni = 0; ni < 4; ++ni) {
        float bsv = bsum[bx * 128 + wn * 64 + ni * 16 + lr];
#pragma unroll
        for (int mi = 0; mi < 4; ++mi) {
            acc[mi][ni][0] = bsv; acc[mi][ni][1] = bsv;
            acc[mi][ni][2] = bsv; acc[mi][ni][3] = bsv;
        }
    }

    int sr = tid >> 1;
    int sc = (tid & 1) * 16;
    const unsigned short* ga = A  + (long)(by * 128 + sr) * 1024 + sc;
    const unsigned short* gb = Bw + (long)(bx * 128 + sr) * 1024 + sc;

    for (int kt = 0; kt < 32; ++kt) {
        uint4 va0 = *(const uint4*)(ga);
        uint4 va1 = *(const uint4*)(ga + 8);
        uint4 vb0 = *(const uint4*)(gb);
        uint4 vb1 = *(const uint4*)(gb + 8);
        *(uint4*)&As[sr][sc]     = va0;
        *(uint4*)&As[sr][sc + 8] = va1;
        *(uint4*)&Bs[sr][sc]     = vb0;
        *(uint4*)&Bs[sr][sc + 8] = vb1;
        __syncthreads();

        bf16x8 af[4], bfr[4];
#pragma unroll
        for (int mi = 0; mi < 4; ++mi)
            af[mi] = *(const bf16x8*)&As[wm * 64 + mi * 16 + lr][lk * 8];
#pragma unroll
        for (int ni = 0; ni < 4; ++ni)
            bfr[ni] = *(const bf16x8*)&Bs[wn * 64 + ni * 16 + lr][lk * 8];
#pragma unroll
        for (int mi = 0; mi < 4; ++mi)
#pragma unroll
            for (int ni = 0; ni < 4; ++ni)
                acc[mi][ni] = __builtin_amdgcn_mfma_f32_16x16x32_bf16(af[mi], bfr[ni], acc[mi][ni], 0, 0, 0);
        __syncthreads();
        ga += 32; gb += 32;
    }

#pragma unroll
    for (int mi = 0; mi < 4; ++mi) {
        int mg = by * 128 + wm * 64 + mi * 16 + lk * 4;
        int tt = mg >> 6;
        int bb = mg & 63;
#pragma unroll
        for (int ni = 0; ni < 4; ++ni) {
            int nn = bx * 128 + wn * 64 + ni * 16 + lr;
            *(f32x4*)(XW + (long)tt * (NGATE * 64) + (long)nn * 64 + bb) = acc[mi][ni];
        }
    }
}

// ---- recurrence: fresh-slot h exchange, L2-broadcast reads -------------
// Identical to round 5 except the barrier poll: ONLY WAVE 0 polls, and it
// covers all 256 flags with one global_load_dwordx4 sc0 sc1 per lane
// (lane l watches flags[4l..4l+3]). This cuts poll traffic at the
// coherence point 4x in bytes and 64x in request count per round.
__global__ __launch_bounds__(256) void lstm_rec(const float* __restrict__ Whh,
                                                const float* __restrict__ XW,
                                                unsigned short* __restrict__ hseq,
                                                unsigned* __restrict__ flags,
                                                float* __restrict__ out) {
    __shared__ float Glds[16][68];
    __shared__ unsigned long long Hs[64];   // pack buffer: Hs[b] = 4 bf16

    int tid = threadIdx.x;
    int w = tid >> 6, l = tid & 63;
    int lr = l & 15, lk = l >> 4;
    int g4 = blockIdx.x * 4;

    // preload W_hh fragments: lane lr -> n_local = q*4+u, gate row q*1024+g4+u
    int q = lr >> 2, u = lr & 3;
    long nrow = (long)(q * 1024 + g4 + u) * 1024;
    bf16x8 wf[32];
#pragma unroll
    for (int kk = 0; kk < 32; ++kk) {
        int k0 = kk * 32 + lk * 8;
        float4 w0 = *(const float4*)(Whh + nrow + k0);
        float4 w1 = *(const float4*)(Whh + nrow + k0 + 4);
        wf[kk] = pack8(w0, w1);
    }

    float c = 0.0f;
    int brow = w * 16 + lr;   // batch row this lane contributes to

    for (int t = 0; t < SEQ; ++t) {
        // slot t, ull view: index g*64 + b  (g in [0,256), b in [0,64))
        const unsigned long long* hc =
            (const unsigned long long*)hseq + (long)t * 8192 + brow;

        // prefetch this step's XW gate values (plain cached loads; in flight
        // under the MFMA phase's h loads)
        float px[4];
#pragma unroll
        for (int qq = 0; qq < 4; ++qq)
            px[qq] = XW[(long)t * (NGATE * 64) + (long)(qq * 1024 + g4 + w) * 64 + l];

        // MFMA phase: wave w computes batches [w*16, w*16+16) x 16 gate cols
        // A-frag k-group kk: k0 = kk*32 + lk*8 -> g0 = kk*8 + lk*2
        f32x4 acc0 = {0.f, 0.f, 0.f, 0.f}, acc1 = {0.f, 0.f, 0.f, 0.f};
#pragma unroll
        for (int kk = 0; kk < 32; kk += 2) {
            int g0 = kk * 8 + lk * 2;
            union { unsigned long long qv[2]; bf16x8 v; } ua, ub;
            ua.qv[0] = hc[(long)g0 * 64];
            ua.qv[1] = hc[(long)(g0 + 1) * 64];
            ub.qv[0] = hc[(long)(g0 + 8) * 64];
            ub.qv[1] = hc[(long)(g0 + 9) * 64];
            acc0 = __builtin_amdgcn_mfma_f32_16x16x32_bf16(ua.v, wf[kk],     acc0, 0, 0, 0);
            acc1 = __builtin_amdgcn_mfma_f32_16x16x32_bf16(ub.v, wf[kk + 1], acc1, 0, 0, 0);
        }
        f32x4 gacc = acc0 + acc1;
        // D: lane holds rows lk*4+r, col lr -> Glds[lr][w*16 + lk*4 + r]
        *(f32x4*)&Glds[lr][w * 16 + lk * 4] = gacc;
        __syncthreads();

        // activation: thread owns batch b=l, hidden unit g4+w  (g=blockIdx, u=w)
        float p[4];
#pragma unroll
        for (int qq = 0; qq < 4; ++qq)
            p[qq] = Glds[qq * 4 + w][l] + px[qq];
        float ig = sigmoidf_(p[0]);
        float fg = sigmoidf_(p[1]);
        float gg = tanhf_(p[2]);
        float og = sigmoidf_(p[3]);
        c = fg * c + ig * gg;
        float h = og * tanhf_(c);

        if (t == SEQ - 1) {
            out[l * HID + g4 + w] = h;
            out[NBATCH * HID + l * HID + g4 + w] = c;
        } else {
            // pack h into LDS: Hs[b=l], halfword u=w
            ((unsigned short*)&Hs[l])[w] = f2bf(h);
            __syncthreads();
            unsigned tv = (unsigned)(t + 1);
            if (tid < 64) {   // wave 0: store, drain, publish, poll
                unsigned long long* hn = (unsigned long long*)hseq +
                                         (long)(t + 1) * 8192 + blockIdx.x * 64;
                __hip_atomic_store(&hn[tid], Hs[tid],
                                   __ATOMIC_RELAXED, __HIP_MEMORY_SCOPE_AGENT);
                asm volatile("s_waitcnt vmcnt(0)" ::: "memory");   // store ack'd at MALL
                if (tid == 0)
                    __hip_atomic_store(&flags[blockIdx.x], tv,
                                       __ATOMIC_RELAXED, __HIP_MEMORY_SCOPE_AGENT);
                // poll: lane l watches flags[4l..4l+3] with ONE bypass dwordx4
                const unsigned* fp = flags + tid * 4;
                long spins = 0;
                for (;;) {
                    uint4 fv;
                    asm volatile("global_load_dwordx4 %0, %1, off sc0 sc1\n\t"
                                 "s_waitcnt vmcnt(0)"
                                 : "=v"(fv) : "v"(fp) : "memory");
                    unsigned mn = fv.x < fv.y ? fv.x : fv.y;
                    unsigned mn2 = fv.z < fv.w ? fv.z : fv.w;
                    if (mn2 < mn) mn = mn2;
                    if (mn >= tv) break;
                    if (++spins > 500000L) break;
                    __builtin_amdgcn_s_sleep(1);
                }
            }
            __syncthreads();            // waves 1-3 gated on wave 0's poll exit
        }
    }
}

// ---- launch ------------------------------------------------------------
extern "C" void kernel_launch(void* const* d_in, const int* in_sizes, int n_in,
                              void* d_out, int out_size, void* d_ws, size_t ws_size,
                              hipStream_t stream) {
    const float* emb  = (const float*)d_in[0];
    const float* W_ih = (const float*)d_in[1];
    const float* W_hh = (const float*)d_in[2];
    const float* b_ih = (const float*)d_in[3];
    const float* b_hh = (const float*)d_in[4];
    const int*   inp  = (const int*)d_in[5];
    float* out = (float*)d_out;

    // workspace layout (~159.4 MiB used); hseq ALIASES Xbf (Xbf is dead
    // after gemm_xw completes; stream ordering makes the reuse safe).
    char* ws = (char*)d_ws;
    float*          XW   = (float*)ws;                            // 134,217,728 B
    unsigned short* Xbf  = (unsigned short*)(ws + 134217728);     //  16,777,216 B
    unsigned short* hseq = Xbf;                                   //  (alias, 128 slots x 128KB)
    unsigned short* Wbf  = (unsigned short*)(ws + 150994944);     //   8,388,608 B
    float*          bs   = (float*)(ws + 159383552);              //      16,384 B
    unsigned*       flags= (unsigned*)(ws + 159399936);           //       1,024 B

    hipMemsetAsync(flags, 0, NBLK * sizeof(unsigned), stream);
    gather_x<<<SEQ * NBATCH, 256, 0, stream>>>(emb, inp, Xbf);
    conv_w<<<NGATE, 256, 0, stream>>>(W_ih, Wbf);
    bsum_k<<<16, 256, 0, stream>>>(b_ih, b_hh, bs);
    gemm_xw<<<dim3(32, 64), 256, 0, stream>>>(Xbf, Wbf, bs, XW);
    // zero h slot 0 (after gemm_xw: hseq aliases Xbf)
    hipMemsetAsync(hseq, 0, NBATCH * HID * sizeof(unsigned short), stream);

    lstm_rec<<<NBLK, 256, 0, stream>>>(W_hh, XW, hseq, flags, out);
}

// Round 7
// 1006.072 us; speedup vs baseline: 4.6702x; 1.0949x over previous
//
#include <hip/hip_runtime.h>
#include <hip/hip_bf16.h>

#define EMB   1024
#define HID   1024
#define NBATCH 64
#define SEQ   128
#define NGATE 4096   // 4*HID
#define NBLK  128    // recurrence grid (each block owns 8 hidden units)

typedef __attribute__((ext_vector_type(8))) short bf16x8;
typedef __attribute__((ext_vector_type(4))) float f32x4;

__device__ __forceinline__ unsigned short f2bf(float f) {
    unsigned int u = __float_as_uint(f);
    unsigned int r = (u + 0x7FFFu + ((u >> 16) & 1u)) >> 16;
    return (unsigned short)r;
}

__device__ __forceinline__ bf16x8 pack8(float4 a, float4 b) {
    bf16x8 r;
    r[0] = (short)f2bf(a.x); r[1] = (short)f2bf(a.y);
    r[2] = (short)f2bf(a.z); r[3] = (short)f2bf(a.w);
    r[4] = (short)f2bf(b.x); r[5] = (short)f2bf(b.y);
    r[6] = (short)f2bf(b.z); r[7] = (short)f2bf(b.w);
    return r;
}

__device__ __forceinline__ float sigmoidf_(float x) { return 1.0f / (1.0f + __expf(-x)); }
__device__ __forceinline__ float tanhf_(float x)    { return 1.0f - 2.0f / (1.0f + __expf(2.0f * x)); }

// ---- prep kernels ------------------------------------------------------

// X[t*64+b][k] = bf16(emb[inputs[b][t]][k]);  grid 8192, block 256
__global__ void gather_x(const float* __restrict__ emb, const int* __restrict__ inp,
                         unsigned short* __restrict__ xbf) {
    int m = blockIdx.x;          // m = t*64 + b
    int t = m >> 6, b = m & 63;
    int tok = inp[b * SEQ + t];
    float4 v = ((const float4*)(emb + (long)tok * EMB))[threadIdx.x];
    ushort4 o;
    o.x = f2bf(v.x); o.y = f2bf(v.y); o.z = f2bf(v.z); o.w = f2bf(v.w);
    ((ushort4*)(xbf + (long)m * EMB))[threadIdx.x] = o;
}

// W_ih -> bf16; grid 4096, block 256
__global__ void conv_w(const float* __restrict__ w, unsigned short* __restrict__ wbf) {
    long i = (long)blockIdx.x * 1024 + (long)threadIdx.x * 4;
    float4 v = *(const float4*)(w + i);
    ushort4 o;
    o.x = f2bf(v.x); o.y = f2bf(v.y); o.z = f2bf(v.z); o.w = f2bf(v.w);
    *(ushort4*)(wbf + i) = o;
}

// bsum = b_ih + b_hh; grid 16, block 256
__global__ void bsum_k(const float* __restrict__ bi, const float* __restrict__ bh,
                       float* __restrict__ bs) {
    int i = blockIdx.x * 256 + threadIdx.x;
    bs[i] = bi[i] + bh[i];
}

// ---- input GEMM: XW[t][n][b] = sum_k X[t*64+b][k]*W_ih[n][k] + bsum[n] ----
__global__ __launch_bounds__(256) void gemm_xw(const unsigned short* __restrict__ A,
                                               const unsigned short* __restrict__ Bw,
                                               const float* __restrict__ bsum,
                                               float* __restrict__ XW) {
    __shared__ unsigned short As[128][40];
    __shared__ unsigned short Bs[128][40];
    int bx = blockIdx.x;             // N tile (0..31)
    int by = blockIdx.y;             // M tile (0..63)
    int tid = threadIdx.x;
    int w = tid >> 6, l = tid & 63;
    int wm = w >> 1, wn = w & 1;
    int lr = l & 15, lk = l >> 4;

    f32x4 acc[4][4];
#pragma unroll
    for (int ni = 0; ni < 4; ++ni) {
        float bsv = bsum[bx * 128 + wn * 64 + ni * 16 + lr];
#pragma unroll
        for (int mi = 0; mi < 4; ++mi) {
            acc[mi][ni][0] = bsv; acc[mi][ni][1] = bsv;
            acc[mi][ni][2] = bsv; acc[mi][ni][3] = bsv;
        }
    }

    int sr = tid >> 1;
    int sc = (tid & 1) * 16;
    const unsigned short* ga = A  + (long)(by * 128 + sr) * 1024 + sc;
    const unsigned short* gb = Bw + (long)(bx * 128 + sr) * 1024 + sc;

    for (int kt = 0; kt < 32; ++kt) {
        uint4 va0 = *(const uint4*)(ga);
        uint4 va1 = *(const uint4*)(ga + 8);
        uint4 vb0 = *(const uint4*)(gb);
        uint4 vb1 = *(const uint4*)(gb + 8);
        *(uint4*)&As[sr][sc]     = va0;
        *(uint4*)&As[sr][sc + 8] = va1;
        *(uint4*)&Bs[sr][sc]     = vb0;
        *(uint4*)&Bs[sr][sc + 8] = vb1;
        __syncthreads();

        bf16x8 af[4], bfr[4];
#pragma unroll
        for (int mi = 0; mi < 4; ++mi)
            af[mi] = *(const bf16x8*)&As[wm * 64 + mi * 16 + lr][lk * 8];
#pragma unroll
        for (int ni = 0; ni < 4; ++ni)
            bfr[ni] = *(const bf16x8*)&Bs[wn * 64 + ni * 16 + lr][lk * 8];
#pragma unroll
        for (int mi = 0; mi < 4; ++mi)
#pragma unroll
            for (int ni = 0; ni < 4; ++ni)
                acc[mi][ni] = __builtin_amdgcn_mfma_f32_16x16x32_bf16(af[mi], bfr[ni], acc[mi][ni], 0, 0, 0);
        __syncthreads();
        ga += 32; gb += 32;
    }

#pragma unroll
    for (int mi = 0; mi < 4; ++mi) {
        int mg = by * 128 + wm * 64 + mi * 16 + lk * 4;
        int tt = mg >> 6;
        int bb = mg & 63;
#pragma unroll
        for (int ni = 0; ni < 4; ++ni) {
            int nn = bx * 128 + wn * 64 + ni * 16 + lr;
            *(f32x4*)(XW + (long)tt * (NGATE * 64) + (long)nn * 64 + bb) = acc[mi][ni];
        }
    }
}

// ---- recurrence: 128 blocks x 512 thr, fresh-slot exchange -------------
// Block g owns hid units g*8..g*8+7 (32 gate rows). 8 waves = 4 batch-groups
// x 2 gate-groups; each wave one 16(batch)x16(gate)x1024 MFMA tile.
// h slot layout per step (128KB, NON-overlapping: stride 16384 ULLs):
//   [g:128][b:64][u:8] bf16 -> chunk g is 1KB contiguous; a reader's
//   A-fragment (8 consecutive hid of one batch) is ONE 16B uint4.
// Writes: agent-scope write-through, vmcnt(0) ack, then flag publish.
// Reads: normal cached loads (fresh addresses, flag-gated => never stale).
__global__ __launch_bounds__(512) void lstm_rec(const float* __restrict__ Whh,
                                                const float* __restrict__ XW,
                                                unsigned short* __restrict__ hseq,
                                                unsigned* __restrict__ flags,
                                                float* __restrict__ out) {
    __shared__ float Glds[32][68];              // [n_local][batch]
    __shared__ unsigned short Hs[64][8];        // h pack: [batch][u]

    int tid = threadIdx.x;
    int w = tid >> 6, l = tid & 63;             // wave, lane
    int lr = l & 15, lk = l >> 4;
    int bg = w & 3, ng = w >> 2;                // batch-group, gate-group
    int g = blockIdx.x;                         // owns hid g*8..g*8+7

    // W_hh fragment preload: lane lr holds gate col n_local = ng*16+lr
    int nl = ng * 16 + lr;
    int q = nl >> 3, u = nl & 7;
    long nrow = (long)(q * 1024 + g * 8 + u) * 1024;
    bf16x8 wf[32];
#pragma unroll
    for (int kk = 0; kk < 32; ++kk) {
        int k0 = kk * 32 + lk * 8;
        float4 w0 = *(const float4*)(Whh + nrow + k0);
        float4 w1 = *(const float4*)(Whh + nrow + k0 + 4);
        wf[kk] = pack8(w0, w1);
    }

    float c = 0.0f;
    int brow = bg * 16 + lr;                    // batch row for A-fragments

    for (int t = 0; t < SEQ; ++t) {
        const uint4* hc = (const uint4*)hseq + (long)t * 8192;  // slot t

        // prefetch this step's XW gate values: thread (b=l, j=w)
        float px[4];
#pragma unroll
        for (int qq = 0; qq < 4; ++qq)
            px[qq] = XW[(long)t * (NGATE * 64) + (long)(qq * 1024 + g * 8 + w) * 64 + l];

        // MFMA: wave (bg,ng) -> batches bg*16.. x gate cols ng*16..
        // frag kk: producing block g' = kk*4+lk; one uint4 = 8 hid of brow
        f32x4 acc0 = {0.f, 0.f, 0.f, 0.f}, acc1 = {0.f, 0.f, 0.f, 0.f};
#pragma unroll
        for (int kk = 0; kk < 32; kk += 2) {
            union { uint4 u4; bf16x8 v; } ua, ub;
            ua.u4 = hc[(kk * 4 + lk) * 64 + brow];
            ub.u4 = hc[((kk + 1) * 4 + lk) * 64 + brow];
            acc0 = __builtin_amdgcn_mfma_f32_16x16x32_bf16(ua.v, wf[kk],     acc0, 0, 0, 0);
            acc1 = __builtin_amdgcn_mfma_f32_16x16x32_bf16(ub.v, wf[kk + 1], acc1, 0, 0, 0);
        }
        f32x4 gacc = acc0 + acc1;
        // D: col(n)=lr, row(batch)=lk*4+r -> Glds[ng*16+lr][bg*16+lk*4+r]
        *(f32x4*)&Glds[ng * 16 + lr][bg * 16 + lk * 4] = gacc;
        __syncthreads();

        // activation: thread owns batch b=l, hid unit g*8+w
        float p[4];
#pragma unroll
        for (int qq = 0; qq < 4; ++qq)
            p[qq] = Glds[qq * 8 + w][l] + px[qq];
        float ig = sigmoidf_(p[0]);
        float fg = sigmoidf_(p[1]);
        float gg = tanhf_(p[2]);
        float og = sigmoidf_(p[3]);
        c = fg * c + ig * gg;
        float h = og * tanhf_(c);

        if (t == SEQ - 1) {
            out[l * HID + g * 8 + w] = h;
            out[NBATCH * HID + l * HID + g * 8 + w] = c;
        } else {
            Hs[l][w] = f2bf(h);
            __syncthreads();
            unsigned tv = (unsigned)(t + 1);
            if (tid < 64) {   // wave 0: store 1KB chunk, ack, publish, poll
                unsigned long long* hn = (unsigned long long*)hseq +
                                         (long)(t + 1) * 16384 + (long)g * 128;
                const unsigned long long* hsu = (const unsigned long long*)Hs;
                __hip_atomic_store(&hn[tid * 2],     hsu[tid * 2],
                                   __ATOMIC_RELAXED, __HIP_MEMORY_SCOPE_AGENT);
                __hip_atomic_store(&hn[tid * 2 + 1], hsu[tid * 2 + 1],
                                   __ATOMIC_RELAXED, __HIP_MEMORY_SCOPE_AGENT);
                asm volatile("s_waitcnt vmcnt(0)" ::: "memory");   // ack'd at MALL
                if (tid == 0)
                    __hip_atomic_store(&flags[g], tv,
                                       __ATOMIC_RELAXED, __HIP_MEMORY_SCOPE_AGENT);
                if (tid < 32) {
                    // lane watches flags[4*tid..4*tid+3]: one bypass dwordx4
                    const unsigned* fp = flags + tid * 4;
                    long spins = 0;
                    for (;;) {
                        uint4 fv;
                        asm volatile("global_load_dwordx4 %0, %1, off sc0 sc1\n\t"
                                     "s_waitcnt vmcnt(0)"
                                     : "=v"(fv) : "v"(fp) : "memory");
                        unsigned mn = fv.x < fv.y ? fv.x : fv.y;
                        unsigned mn2 = fv.z < fv.w ? fv.z : fv.w;
                        if (mn2 < mn) mn = mn2;
                        if (mn >= tv) break;
                        if (++spins > 500000L) break;
                        __builtin_amdgcn_s_sleep(1);
                    }
                }
            }
            __syncthreads();            // all waves gated on wave 0's poll exit
        }
    }
}

// ---- launch ------------------------------------------------------------
extern "C" void kernel_launch(void* const* d_in, const int* in_sizes, int n_in,
                              void* d_out, int out_size, void* d_ws, size_t ws_size,
                              hipStream_t stream) {
    const float* emb  = (const float*)d_in[0];
    const float* W_ih = (const float*)d_in[1];
    const float* W_hh = (const float*)d_in[2];
    const float* b_ih = (const float*)d_in[3];
    const float* b_hh = (const float*)d_in[4];
    const int*   inp  = (const int*)d_in[5];
    float* out = (float*)d_out;

    // workspace layout; hseq ALIASES Xbf (dead after gemm_xw; 128 slots x
    // 128KB = 16MB fits the 16.77MB Xbf region; slots now NON-overlapping).
    char* ws = (char*)d_ws;
    float*          XW   = (float*)ws;                            // 134,217,728 B
    unsigned short* Xbf  = (unsigned short*)(ws + 134217728);     //  16,777,216 B
    unsigned short* hseq = Xbf;                                   //  (alias)
    unsigned short* Wbf  = (unsigned short*)(ws + 150994944);     //   8,388,608 B
    float*          bs   = (float*)(ws + 159383552);              //      16,384 B
    unsigned*       flags= (unsigned*)(ws + 159399936);           //         512 B

    hipMemsetAsync(flags, 0, NBLK * sizeof(unsigned), stream);
    gather_x<<<SEQ * NBATCH, 256, 0, stream>>>(emb, inp, Xbf);
    conv_w<<<NGATE, 256, 0, stream>>>(W_ih, Wbf);
    bsum_k<<<16, 256, 0, stream>>>(b_ih, b_hh, bs);
    gemm_xw<<<dim3(32, 64), 256, 0, stream>>>(Xbf, Wbf, bs, XW);
    // zero h slot 0 (after gemm_xw: hseq aliases Xbf)
    hipMemsetAsync(hseq, 0, NBATCH * HID * sizeof(unsigned short), stream);

    lstm_rec<<<NBLK, 512, 0, stream>>>(W_hh, XW, hseq, flags, out);
}